// Round 1
// baseline (45.872 us; speedup 1.0000x reference)
//
#include <hip/hip_runtime.h>

// CrossNet fused: one block per row. Closed form x_k = x*c_k + cumsum(b),
// c_k per-row scalar from 3 dot products + 2 shared constants.
// N = 4096, BLK = 256 -> 4 float4 chunks per thread.

constexpr int BLK = 256;

__global__ __launch_bounds__(BLK) void crossnet_fused(
    const float* __restrict__ x,
    const float* __restrict__ w,
    const float* __restrict__ b,
    float* __restrict__ out,
    int B, int N)
{
    const int row = blockIdx.x;
    const int tid = threadIdx.x;

    const size_t base = (size_t)row * N;
    const float4* x4 = (const float4*)(x + base);
    const float4* w0 = (const float4*)(w);
    const float4* w1 = (const float4*)(w + N);
    const float4* w2 = (const float4*)(w + 2 * (size_t)N);
    const float4* b0 = (const float4*)(b);
    const float4* b1 = (const float4*)(b + N);
    const float4* b2 = (const float4*)(b + 2 * (size_t)N);

    // Register-resident row data: x, and cumulative bias sums
    float4 xv[4];
    float4 cb1v[4];  // b0
    float4 cb2v[4];  // b0+b1
    float4 cb3v[4];  // b0+b1+b2

    float p0 = 0.f, p1 = 0.f, p2 = 0.f;  // x . w0/w1/w2 partials
    float q1 = 0.f, q2 = 0.f;            // b0 . w1, (b0+b1) . w2 partials

    #pragma unroll
    for (int c = 0; c < 4; ++c) {
        const int idx = c * BLK + tid;     // float4 index within the row
        const float4 xx = x4[idx];
        const float4 wa = w0[idx];
        const float4 wb = w1[idx];
        const float4 wc = w2[idx];
        const float4 ba = b0[idx];
        const float4 bb = b1[idx];
        const float4 bc = b2[idx];

        xv[c] = xx;
        float4 c1v = ba;
        float4 c2v = make_float4(ba.x + bb.x, ba.y + bb.y, ba.z + bb.z, ba.w + bb.w);
        float4 c3v = make_float4(c2v.x + bc.x, c2v.y + bc.y, c2v.z + bc.z, c2v.w + bc.w);
        cb1v[c] = c1v; cb2v[c] = c2v; cb3v[c] = c3v;

        p0 += xx.x * wa.x + xx.y * wa.y + xx.z * wa.z + xx.w * wa.w;
        p1 += xx.x * wb.x + xx.y * wb.y + xx.z * wb.z + xx.w * wb.w;
        p2 += xx.x * wc.x + xx.y * wc.y + xx.z * wc.z + xx.w * wc.w;
        q1 += c1v.x * wb.x + c1v.y * wb.y + c1v.z * wb.z + c1v.w * wb.w;
        q2 += c2v.x * wc.x + c2v.y * wc.y + c2v.z * wc.z + c2v.w * wc.w;
    }

    // Wave-level butterfly reduce (64 lanes)
    #pragma unroll
    for (int off = 32; off > 0; off >>= 1) {
        p0 += __shfl_down(p0, off);
        p1 += __shfl_down(p1, off);
        p2 += __shfl_down(p2, off);
        q1 += __shfl_down(q1, off);
        q2 += __shfl_down(q2, off);
    }

    __shared__ float red[4][8];
    const int wave = tid >> 6;
    const int lane = tid & 63;
    if (lane == 0) {
        red[wave][0] = p0; red[wave][1] = p1; red[wave][2] = p2;
        red[wave][3] = q1; red[wave][4] = q2;
    }
    __syncthreads();

    const float u0 = red[0][0] + red[1][0] + red[2][0] + red[3][0];
    const float u1 = red[0][1] + red[1][1] + red[2][1] + red[3][1];
    const float u2 = red[0][2] + red[1][2] + red[2][2] + red[3][2];
    const float t1 = red[0][3] + red[1][3] + red[2][3] + red[3][3];
    const float t2 = red[0][4] + red[1][4] + red[2][4] + red[3][4];

    // scalar recurrence
    const float c1 = 1.0f + u0;            // x1 = x*c1 + b0
    const float s1 = c1 * u1 + t1;
    const float c2 = c1 + s1;              // x2 = x*c2 + b0+b1
    const float s2 = c2 * u2 + t2;
    const float c3 = c2 + s2;              // x3 = x*c3 + b0+b1+b2

    float4* o0 = (float4*)(out + base);
    float4* o1 = (float4*)(out + (size_t)B * N + base);
    float4* o2 = (float4*)(out + 2 * (size_t)B * N + base);

    #pragma unroll
    for (int c = 0; c < 4; ++c) {
        const int idx = c * BLK + tid;
        float4 r0, r1, r2;
        r0.x = fmaf(xv[c].x, c1, cb1v[c].x);
        r0.y = fmaf(xv[c].y, c1, cb1v[c].y);
        r0.z = fmaf(xv[c].z, c1, cb1v[c].z);
        r0.w = fmaf(xv[c].w, c1, cb1v[c].w);
        r1.x = fmaf(xv[c].x, c2, cb2v[c].x);
        r1.y = fmaf(xv[c].y, c2, cb2v[c].y);
        r1.z = fmaf(xv[c].z, c2, cb2v[c].z);
        r1.w = fmaf(xv[c].w, c2, cb2v[c].w);
        r2.x = fmaf(xv[c].x, c3, cb3v[c].x);
        r2.y = fmaf(xv[c].y, c3, cb3v[c].y);
        r2.z = fmaf(xv[c].z, c3, cb3v[c].z);
        r2.w = fmaf(xv[c].w, c3, cb3v[c].w);
        o0[idx] = r0;
        o1[idx] = r1;
        o2[idx] = r2;
    }
}

extern "C" void kernel_launch(void* const* d_in, const int* in_sizes, int n_in,
                              void* d_out, int out_size, void* d_ws, size_t ws_size,
                              hipStream_t stream) {
    const float* x = (const float*)d_in[0];
    const float* w = (const float*)d_in[1];
    const float* b = (const float*)d_in[2];
    float* out = (float*)d_out;

    const int N = in_sizes[1] / 3;   // w is [3, N, 1]
    const int B = in_sizes[0] / N;   // x is [B, N]

    crossnet_fused<<<B, BLK, 0, stream>>>(x, w, b, out, B, N);
}